// Round 17
// baseline (5169.657 us; speedup 1.0000x reference)
//
#include <hip/hip_runtime.h>
#include <hip/hip_bf16.h>
#include <cstdint>
#include <cstddef>

#define VOCAB  4096
#define HIDDEN 1024
#define BATCH  64
#define SEQ    256
#define NWG    64       // 4 scans x 16 WGs; 256 threads (4 waves) each
#define SCANS  4

typedef __attribute__((ext_vector_type(8))) short short8;
typedef __attribute__((ext_vector_type(4))) float f32x4;

__device__ __forceinline__ unsigned short f2bf(float f) {
    union { float f; uint32_t u; } v; v.f = f;
    uint32_t u = v.u;
    u += 0x7FFFu + ((u >> 16) & 1u);   // round-to-nearest-even
    return (unsigned short)(u >> 16);
}

// device-scope (agent) relaxed atomic store — uncached at LLC (proven r4-r14)
__device__ __forceinline__ void ast16(unsigned short* p, unsigned short v) {
    __hip_atomic_store(p, v, __ATOMIC_RELAXED, __HIP_MEMORY_SCOPE_AGENT);
}

// coherent 16B load: bypasses L1/L2 (sc0 sc1), order-pinned volatile asm (proven r7)
__device__ __forceinline__ short8 cld16(const unsigned short* p) {
    short8 v;
    asm volatile("global_load_dwordx4 %0, %1, off sc0 sc1"
                 : "=v"(v) : "v"(p) : "memory");
    return v;
}

// ---------------- zero init H + barrier flags ----------------
__global__ __launch_bounds__(256) void k_zero(float* Hf, unsigned short* Hbf, int* flags) {
    int i = blockIdx.x * 256 + threadIdx.x;
    if (i < BATCH * HIDDEN) { Hf[i] = 0.f; Hbf[i] = 0; }
    if (i < 2048) flags[i] = 0;
}

// ---------------- transpose+pack: src f32 [R][C] -> dst bf16 [C][R] ----------------
__global__ __launch_bounds__(256) void k_pack(const float* __restrict__ src,
                                              unsigned short* __restrict__ dst,
                                              int R, int C) {
    __shared__ float tile[32][33];
    int tilesC = C >> 5;
    int bx = blockIdx.x % tilesC;
    int by = blockIdx.x / tilesC;
    int tx = threadIdx.x & 31;
    int ty = threadIdx.x >> 5;
    int c0 = bx << 5, r0 = by << 5;
    #pragma unroll
    for (int s = 0; s < 4; ++s) {
        int r = ty + s * 8;
        tile[r][tx] = src[(size_t)(r0 + r) * C + (c0 + tx)];
    }
    __syncthreads();
    #pragma unroll
    for (int s = 0; s < 4; ++s) {
        int cc = ty + s * 8;
        dst[(size_t)(c0 + cc) * R + (r0 + tx)] = f2bf(tile[tx][cc]);
    }
}

// ---------------- per-scan flag barrier (multi-wave WG; r13-proven shape) ----------------
__device__ __forceinline__ void grp_barrier(int* flags, int base, int idx, int p) {
    asm volatile("s_waitcnt vmcnt(0)" ::: "memory");   // all data stores at LLC
    __syncthreads();
    if (threadIdx.x == 0)
        __hip_atomic_store(&flags[base + idx], p, __ATOMIC_RELAXED, __HIP_MEMORY_SCOPE_AGENT);
    if (threadIdx.x < 16) {
        while (__hip_atomic_load(&flags[base + (int)threadIdx.x],
                                 __ATOMIC_RELAXED, __HIP_MEMORY_SCOPE_AGENT) < p)
            __builtin_amdgcn_s_sleep(1);
    }
    __syncthreads();
    __builtin_amdgcn_sched_barrier(0);   // rule #18
}

// ---------------- persistent GRU scan: LDS-shared A, L2-streamed weights ----------------
// WG g: scan=g>>4 (rows [16s,16s+16)), wgc=g&15 (cols [64wgc,64wgc+64)). 4 waves,
// wave v owns cols [64wgc+16v, +16). The 16-row A-slice (32KB) is staged ONCE into
// LDS (uncached reads) and shared by all 4 waves -> exchange traffic 4x lower.
__global__ __launch_bounds__(256, 1) void k_scan(
    const int* __restrict__ X,
    const float* __restrict__ Wz, const float* __restrict__ bz,
    const float* __restrict__ Wr, const float* __restrict__ br,
    const float* __restrict__ Wh, const float* __restrict__ bh,
    const unsigned short* __restrict__ Wzh, const unsigned short* __restrict__ Wrh,
    const unsigned short* __restrict__ Whh,
    float* __restrict__ Hf, unsigned short* __restrict__ Hbf,
    unsigned short* __restrict__ rHbf, unsigned short* __restrict__ Hhist,
    int* __restrict__ flags)
{
    __shared__ __align__(16) unsigned short ALD[16 * 1024];   // 32KB A-stage

    const int tid  = threadIdx.x;
    const int g    = blockIdx.x;
    const int scan = g >> 4;            // 0..3
    const int wgc  = g & 15;            // 0..15
    const int wv   = tid >> 6;          // wave 0..3
    const int lane = tid & 63;
    const int row  = lane & 15;
    const int q    = lane >> 4;
    const int kq   = q << 3;
    const int j    = (wgc << 6) + (wv << 4) + row;   // wave's owned col
    const int b0   = scan << 4;
    const int bq   = b0 + (q << 2);
    const int fbase = scan << 4;        // 16 flags per scan

    const float bzj = bz[j], brj = br[j], bhj = bh[j];
    const unsigned short* wzp = Wzh + (size_t)j * HIDDEN + kq;
    const unsigned short* wrp = Wrh + (size_t)j * HIDDEN + kq;
    const unsigned short* whp = Whh + (size_t)j * HIDDEN + kq;

    float zreg[4] = {0.f, 0.f, 0.f, 0.f};
    float Hreg[4] = {0.f, 0.f, 0.f, 0.f};
    int p = 0;

    int tokc[4];
    #pragma unroll
    for (int r = 0; r < 4; ++r) tokc[r] = X[(bq + r) * SEQ + 0];

    for (int t = 0; t < SEQ; ++t) {
        const int tn = (t + 1 < SEQ) ? t + 1 : t;
        int tokn[4];

        // ---------------- phase 1: z and r ----------------
        {
            // stage Hbf rows [b0,b0+16) (32KB) into ALD, XOR-swizzled
            {
                short8 tmp[8];
                #pragma unroll
                for (int c = 0; c < 8; ++c) {
                    int ch = (tid << 3) + c;          // 0..2047
                    int rw = ch >> 7;                 // row 0..15
                    int k8 = ch & 127;                // 8-ushort chunk in row
                    tmp[c] = cld16(Hbf + (size_t)(b0 + rw) * HIDDEN + (k8 << 3));
                }
                asm volatile("s_waitcnt vmcnt(0)" ::: "memory");
                __builtin_amdgcn_sched_barrier(0);
                #pragma unroll
                for (int c = 0; c < 8; ++c) {
                    int ch = (tid << 3) + c;
                    int rw = ch >> 7;
                    int k8 = ch & 127;
                    int ui = ((rw << 10) + (k8 << 3)) ^ ((rw & 7) << 3);
                    *(short8*)&ALD[ui] = tmp[c];
                }
                __syncthreads();
            }

            // current-step embedding gathers + next-step tokens (plain, compiler-waited)
            float ez[4], er[4], eh[4];
            #pragma unroll
            for (int r = 0; r < 4; ++r) {
                size_t eo = (size_t)tokc[r] * HIDDEN + j;
                ez[r] = Wz[eo]; er[r] = Wr[eo]; eh[r] = Wh[eo];
                tokn[r] = X[(bq + r) * SEQ + tn];
            }

            f32x4 accZ = {0.f, 0.f, 0.f, 0.f}, accR = {0.f, 0.f, 0.f, 0.f};
            #pragma unroll 8
            for (int kk = 0; kk < 32; ++kk) {
                int ai = ((row << 10) + (kk << 5) + kq) ^ ((row & 7) << 3);
                short8 a  = *(const short8*)&ALD[ai];
                short8 fz = *(const short8*)(wzp + kk * 32);   // L2-hot cached
                short8 fr = *(const short8*)(wrp + kk * 32);
                accZ = __builtin_amdgcn_mfma_f32_16x16x32_bf16(a, fz, accZ, 0, 0, 0);
                accR = __builtin_amdgcn_mfma_f32_16x16x32_bf16(a, fr, accR, 0, 0, 0);
            }
            #pragma unroll
            for (int r = 0; r < 4; ++r) {
                float rv = 1.f / (1.f + expf(-(accR[r] + er[r] + brj)));
                ast16(&rHbf[(bq + r) * HIDDEN + j], f2bf(rv * Hreg[r]));
                zreg[r] = 1.f / (1.f + expf(-(accZ[r] + ez[r] + bzj)));
            }
            // eh needed in phase 2 epilogue: carry in registers
            #pragma unroll
            for (int r = 0; r < 4; ++r) zreg[r] = zreg[r];   // no-op, keep structure clear
            // (eh[] stays live into phase 2 below)
            grp_barrier(flags, fbase, wgc, ++p);

            // ---------------- phase 2: h + state update ----------------
            {
                short8 tmp[8];
                #pragma unroll
                for (int c = 0; c < 8; ++c) {
                    int ch = (tid << 3) + c;
                    int rw = ch >> 7;
                    int k8 = ch & 127;
                    tmp[c] = cld16(rHbf + (size_t)(b0 + rw) * HIDDEN + (k8 << 3));
                }
                asm volatile("s_waitcnt vmcnt(0)" ::: "memory");
                __builtin_amdgcn_sched_barrier(0);
                #pragma unroll
                for (int c = 0; c < 8; ++c) {
                    int ch = (tid << 3) + c;
                    int rw = ch >> 7;
                    int k8 = ch & 127;
                    int ui = ((rw << 10) + (k8 << 3)) ^ ((rw & 7) << 3);
                    *(short8*)&ALD[ui] = tmp[c];
                }
                __syncthreads();
            }

            f32x4 accH = {0.f, 0.f, 0.f, 0.f};
            #pragma unroll 8
            for (int kk = 0; kk < 32; ++kk) {
                int ai = ((row << 10) + (kk << 5) + kq) ^ ((row & 7) << 3);
                short8 a  = *(const short8*)&ALD[ai];
                short8 fh = *(const short8*)(whp + kk * 32);   // L2-hot cached
                accH = __builtin_amdgcn_mfma_f32_16x16x32_bf16(a, fh, accH, 0, 0, 0);
            }
            #pragma unroll
            for (int r = 0; r < 4; ++r) {
                int b = bq + r;
                float h  = tanhf(accH[r] + eh[r] + bhj);
                float Hn = zreg[r] * h + (1.f - zreg[r]) * Hreg[r];
                Hreg[r] = Hn;
                unsigned short bfv = f2bf(Hn);
                ast16(&Hbf[b * HIDDEN + j], bfv);
                Hhist[(size_t)t * (BATCH * HIDDEN) + b * HIDDEN + j] = bfv;
                if (t == SEQ - 1) Hf[b * HIDDEN + j] = Hn;
            }
            grp_barrier(flags, fbase, wgc, ++p);
        }

        #pragma unroll
        for (int r = 0; r < 4; ++r) tokc[r] = tokn[r];
    }
}

// ---------------- fallback step kernels (round-1 proven) ----------------
__global__ __launch_bounds__(256) void k_step1(
    const int* __restrict__ X,
    const float* __restrict__ Wz, const float* __restrict__ bz,
    const float* __restrict__ Wr, const float* __restrict__ br,
    const unsigned short* __restrict__ Wzh, const unsigned short* __restrict__ Wrh,
    const unsigned short* __restrict__ Hbf, const float* __restrict__ Hf,
    float* __restrict__ zbuf, unsigned short* __restrict__ rHbf, int t)
{
    int w    = threadIdx.x >> 6;
    int lane = threadIdx.x & 63;
    int nt = blockIdx.x;
    int mt = w;
    bool isz = nt < 64;
    const unsigned short* W = isz ? Wzh : Wrh;
    int ntl = nt & 63;
    int row = lane & 15;
    int kq  = (lane >> 4) << 3;
    const unsigned short* aptr = Hbf + (size_t)(mt * 16 + row) * HIDDEN + kq;
    const unsigned short* bptr = W   + (size_t)(ntl * 16 + row) * HIDDEN + kq;
    f32x4 acc = {0.f, 0.f, 0.f, 0.f};
    #pragma unroll 8
    for (int kk = 0; kk < HIDDEN / 32; ++kk) {
        short8 a = *(const short8*)(aptr + kk * 32);
        short8 b = *(const short8*)(bptr + kk * 32);
        acc = __builtin_amdgcn_mfma_f32_16x16x32_bf16(a, b, acc, 0, 0, 0);
    }
    int j = ntl * 16 + row;
    const float* Wemb = isz ? Wz : Wr;
    float bias = isz ? bz[j] : br[j];
    #pragma unroll
    for (int r = 0; r < 4; ++r) {
        int b = mt * 16 + ((lane >> 4) << 2) + r;
        int tok = X[b * SEQ + t];
        float pre = acc[r] + Wemb[(size_t)tok * HIDDEN + j] + bias;
        float s = 1.f / (1.f + expf(-pre));
        if (isz) zbuf[b * HIDDEN + j] = s;
        else     rHbf[b * HIDDEN + j] = f2bf(s * Hf[b * HIDDEN + j]);
    }
}

__global__ __launch_bounds__(256) void k_step2(
    const int* __restrict__ X,
    const float* __restrict__ Wh, const float* __restrict__ bh,
    const unsigned short* __restrict__ Whh,
    const unsigned short* __restrict__ rHbf,
    const float* __restrict__ zbuf,
    float* __restrict__ Hf, unsigned short* __restrict__ Hbf,
    unsigned short* __restrict__ Hhist, int t)
{
    int w    = threadIdx.x >> 6;
    int lane = threadIdx.x & 63;
    int nt = blockIdx.x;
    int mt = w;
    int row = lane & 15;
    int kq  = (lane >> 4) << 3;
    const unsigned short* aptr = rHbf + (size_t)(mt * 16 + row) * HIDDEN + kq;
    const unsigned short* bptr = Whh  + (size_t)(nt * 16 + row) * HIDDEN + kq;
    f32x4 acc = {0.f, 0.f, 0.f, 0.f};
    #pragma unroll 8
    for (int kk = 0; kk < HIDDEN / 32; ++kk) {
        short8 a = *(const short8*)(aptr + kk * 32);
        short8 b = *(const short8*)(bptr + kk * 32);
        acc = __builtin_amdgcn_mfma_f32_16x16x32_bf16(a, b, acc, 0, 0, 0);
    }
    int j = nt * 16 + row;
    float bias = bh[j];
    #pragma unroll
    for (int r = 0; r < 4; ++r) {
        int b = mt * 16 + ((lane >> 4) << 2) + r;
        int tok = X[b * SEQ + t];
        float pre = acc[r] + Wh[(size_t)tok * HIDDEN + j] + bias;
        float h = tanhf(pre);
        float z = zbuf[b * HIDDEN + j];
        float Hold = Hf[b * HIDDEN + j];
        float Hn = z * h + (1.f - z) * Hold;
        Hf[b * HIDDEN + j] = Hn;
        unsigned short bf = f2bf(Hn);
        Hbf[b * HIDDEN + j] = bf;
        Hhist[(size_t)t * (BATCH * HIDDEN) + b * HIDDEN + j] = bf;
    }
}

// ---------------- output projection ----------------
__global__ __launch_bounds__(256) void k_out(
    const unsigned short* __restrict__ A,
    const unsigned short* __restrict__ B,
    const float* __restrict__ bo,
    float* __restrict__ out)
{
    __shared__ __align__(16) unsigned short As[128 * 32];
    __shared__ __align__(16) unsigned short Bs[128 * 32];
    int bn = blockIdx.x & 31;
    int bm = blockIdx.x >> 5;
    int m0 = bm << 7, n0 = bn << 7;
    int tid  = threadIdx.x;
    int w    = tid >> 6, lane = tid & 63;
    int wm = w & 1, wn = w >> 1;
    int row = lane & 15;
    int kq  = (lane >> 4) << 3;

    f32x4 acc[4][4];
    #pragma unroll
    for (int i = 0; i < 4; ++i)
        #pragma unroll
        for (int jj = 0; jj < 4; ++jj)
            acc[i][jj] = (f32x4){0.f, 0.f, 0.f, 0.f};

    for (int k0 = 0; k0 < HIDDEN; k0 += 32) {
        #pragma unroll
        for (int c = 0; c < 2; ++c) {
            int off  = tid * 32 + c * 16;
            int rowi = off >> 6;
            int us   = (off & 63) >> 1;
            *(short8*)&As[rowi * 32 + us] =
                *(const short8*)&A[(size_t)(m0 + rowi) * HIDDEN + k0 + us];
            *(short8*)&Bs[rowi * 32 + us] =
                *(const short8*)&B[(size_t)(n0 + rowi) * HIDDEN + k0 + us];
        }
        __syncthreads();
        short8 a[4], b[4];
        #pragma unroll
        for (int i = 0; i < 4; ++i)
            a[i] = *(const short8*)&As[(wm * 64 + i * 16 + row) * 32 + kq];
        #pragma unroll
        for (int jj = 0; jj < 4; ++jj)
            b[jj] = *(const short8*)&Bs[(wn * 64 + jj * 16 + row) * 32 + kq];
        #pragma unroll
        for (int i = 0; i < 4; ++i)
            #pragma unroll
            for (int jj = 0; jj < 4; ++jj)
                acc[i][jj] = __builtin_amdgcn_mfma_f32_16x16x32_bf16(a[i], b[jj], acc[i][jj], 0, 0, 0);
        __syncthreads();
    }

    #pragma unroll
    for (int i = 0; i < 4; ++i) {
        #pragma unroll
        for (int jj = 0; jj < 4; ++jj) {
            int n = n0 + wn * 64 + jj * 16 + row;
            float bb = bo[n];
            #pragma unroll
            for (int r = 0; r < 4; ++r) {
                int m = m0 + wm * 64 + i * 16 + ((lane >> 4) << 2) + r;
                out[(size_t)m * VOCAB + n] = acc[i][jj][r] + bb;
            }
        }
    }
}

// ---------------- H_final copy ----------------
__global__ __launch_bounds__(256) void k_copyH(const float* __restrict__ Hf,
                                               float* __restrict__ out) {
    int i = blockIdx.x * 256 + threadIdx.x;
    if (i < BATCH * HIDDEN)
        out[(size_t)SEQ * BATCH * VOCAB + i] = Hf[i];
}

extern "C" void kernel_launch(void* const* d_in, const int* in_sizes, int n_in,
                              void* d_out, int out_size, void* d_ws, size_t ws_size,
                              hipStream_t stream) {
    const int*   X  = (const int*)  d_in[0];
    const float* Wz = (const float*)d_in[1];
    const float* bz = (const float*)d_in[2];
    const float* Wr = (const float*)d_in[3];
    const float* br = (const float*)d_in[4];
    const float* Wh = (const float*)d_in[5];
    const float* bh = (const float*)d_in[6];
    const float* Wo = (const float*)d_in[7];
    const float* bo = (const float*)d_in[8];
    float* out = (float*)d_out;
    char* ws = (char*)d_ws;

    float*          Hf    = (float*)(ws);                           // 256KB
    float*          zbuf  = (float*)(ws + (256 << 10));             // 256KB (fallback only)
    int*            flags = (int*)(ws + (512 << 10));               // 8KB
    unsigned short* Hbf   = (unsigned short*)(ws + (528 << 10));    // 128KB
    unsigned short* rHbf  = (unsigned short*)(ws + (656 << 10));    // 128KB
    unsigned short* Wzh   = (unsigned short*)(ws + (1 << 20));      // 2MB
    unsigned short* Wrh   = Wzh + 1024 * 1024;                      // 2MB
    unsigned short* Whh   = Wrh + 1024 * 1024;                      // 2MB
    unsigned short* WoT   = Whh + 1024 * 1024;                      // 8MB
    unsigned short* Hhist = WoT + (size_t)VOCAB * HIDDEN;           // 32MB

    k_zero<<<256, 256, 0, stream>>>(Hf, Hbf, flags);
    k_pack<<<32 * 32,  256, 0, stream>>>(Wz + (size_t)VOCAB * HIDDEN, Wzh, 1024, 1024);
    k_pack<<<32 * 32,  256, 0, stream>>>(Wr + (size_t)VOCAB * HIDDEN, Wrh, 1024, 1024);
    k_pack<<<32 * 32,  256, 0, stream>>>(Wh + (size_t)VOCAB * HIDDEN, Whh, 1024, 1024);
    k_pack<<<32 * 128, 256, 0, stream>>>(Wo, WoT, 1024, 4096);

    void* args[] = {
        (void*)&X, (void*)&Wz, (void*)&bz, (void*)&Wr, (void*)&br,
        (void*)&Wh, (void*)&bh, (void*)&Wzh, (void*)&Wrh, (void*)&Whh,
        (void*)&Hf, (void*)&Hbf, (void*)&rHbf, (void*)&Hhist, (void*)&flags
    };
    hipError_t cerr = hipLaunchCooperativeKernel((void*)k_scan, dim3(NWG), dim3(256),
                                                 args, 0, stream);
    if (cerr != hipSuccess) {
        for (int t = 0; t < SEQ; ++t) {
            k_step1<<<128, 256, 0, stream>>>(X, Wz, bz, Wr, br, Wzh, Wrh, Hbf, Hf, zbuf, rHbf, t);
            k_step2<<<64,  256, 0, stream>>>(X, Wh, bh, Whh, rHbf, zbuf, Hf, Hbf, Hhist, t);
        }
    }

    k_out<<<4096, 256, 0, stream>>>(Hhist, WoT, bo, out);
    k_copyH<<<256, 256, 0, stream>>>(Hf, out);
}

// Round 18
// 3054.219 us; speedup vs baseline: 1.6926x; 1.6926x over previous
//
#include <hip/hip_runtime.h>
#include <hip/hip_bf16.h>
#include <cstdint>
#include <cstddef>

#define VOCAB  4096
#define HIDDEN 1024
#define BATCH  64
#define SEQ    256
#define NWG    256      // 4 scans x 64 col-groups; 64 threads (1 wave) each
#define SCANS  4

typedef __attribute__((ext_vector_type(8))) short short8;
typedef __attribute__((ext_vector_type(4))) float f32x4;

__device__ __forceinline__ unsigned short f2bf(float f) {
    union { float f; uint32_t u; } v; v.f = f;
    uint32_t u = v.u;
    u += 0x7FFFu + ((u >> 16) & 1u);   // round-to-nearest-even
    return (unsigned short)(u >> 16);
}

// device-scope (agent) relaxed atomic store — uncached at LLC (proven r4-r14)
__device__ __forceinline__ void ast16(unsigned short* p, unsigned short v) {
    __hip_atomic_store(p, v, __ATOMIC_RELAXED, __HIP_MEMORY_SCOPE_AGENT);
}

// coherent 16B load: bypasses L1/L2 (sc0 sc1), order-pinned volatile asm (proven r7)
__device__ __forceinline__ short8 cld16(const unsigned short* p) {
    short8 v;
    asm volatile("global_load_dwordx4 %0, %1, off sc0 sc1"
                 : "=v"(v) : "v"(p) : "memory");
    return v;
}

// ---------------- zero init H + barrier flags ----------------
__global__ __launch_bounds__(256) void k_zero(float* Hf, unsigned short* Hbf, int* flags) {
    int i = blockIdx.x * 256 + threadIdx.x;
    if (i < BATCH * HIDDEN) { Hf[i] = 0.f; Hbf[i] = 0; }
    if (i < 2048) flags[i] = 0;
}

// ---------------- transpose+pack: src f32 [R][C] -> dst bf16 [C][R] ----------------
__global__ __launch_bounds__(256) void k_pack(const float* __restrict__ src,
                                              unsigned short* __restrict__ dst,
                                              int R, int C) {
    __shared__ float tile[32][33];
    int tilesC = C >> 5;
    int bx = blockIdx.x % tilesC;
    int by = blockIdx.x / tilesC;
    int tx = threadIdx.x & 31;
    int ty = threadIdx.x >> 5;
    int c0 = bx << 5, r0 = by << 5;
    #pragma unroll
    for (int s = 0; s < 4; ++s) {
        int r = ty + s * 8;
        tile[r][tx] = src[(size_t)(r0 + r) * C + (c0 + tx)];
    }
    __syncthreads();
    #pragma unroll
    for (int s = 0; s < 4; ++s) {
        int cc = ty + s * 8;
        dst[(size_t)(c0 + cc) * R + (r0 + tx)] = f2bf(tile[tx][cc]);
    }
}

// ---------------- per-scan barrier (single-wave WG: no syncthreads needed) ----------------
// lane l polls flags[scan*64 + l]; divergent exits reconverge when all 64 flags pass.
__device__ __forceinline__ void scan_barrier(int* flags, int base, int cg, int p) {
    asm volatile("s_waitcnt vmcnt(0)" ::: "memory");   // this wave's stores at LLC
    if (threadIdx.x == 0)
        __hip_atomic_store(&flags[base + cg], p, __ATOMIC_RELAXED, __HIP_MEMORY_SCOPE_AGENT);
    int l = threadIdx.x & 63;
    while (__hip_atomic_load(&flags[base + l], __ATOMIC_RELAXED, __HIP_MEMORY_SCOPE_AGENT) < p)
        __builtin_amdgcn_s_sleep(1);
    __builtin_amdgcn_sched_barrier(0);   // rule #18
}

// ---------------- persistent GRU scan: 4 independent batch-sliced scans ----------------
// WG g: scan s = g>>6 (batch rows [16s,16s+16)), col-group cg = g&63 (cols [16cg,16cg+16)).
// 64 threads (1 wave). All 3 weight slices in LDS (96KB). Exchange via uncached LLC ops.
// Scans are mutually unsynchronized -> their memory phases interleave, filling latency bubbles.
__global__ __launch_bounds__(64, 1) void k_scan(
    const int* __restrict__ X,
    const float* __restrict__ Wz, const float* __restrict__ bz,
    const float* __restrict__ Wr, const float* __restrict__ br,
    const float* __restrict__ Wh, const float* __restrict__ bh,
    const unsigned short* __restrict__ Wzh, const unsigned short* __restrict__ Wrh,
    const unsigned short* __restrict__ Whh,
    float* __restrict__ Hf, unsigned short* __restrict__ Hbf,
    unsigned short* __restrict__ rHbf, unsigned short* __restrict__ Hhist,
    int* __restrict__ flags)
{
    __shared__ __align__(16) unsigned short WzL[16 * 1024];   // 32KB
    __shared__ __align__(16) unsigned short WrL[16 * 1024];   // 32KB
    __shared__ __align__(16) unsigned short WhL[16 * 1024];   // 32KB

    const int tid  = threadIdx.x;       // 0..63 (one wave)
    const int g    = blockIdx.x;
    const int scan = g >> 6;            // 0..3
    const int cg   = g & 63;            // col group
    const int lane = tid & 63;
    const int row  = lane & 15;
    const int q    = lane >> 4;
    const int kq   = q << 3;
    const int col0 = cg << 4;
    const int j    = col0 + row;
    const int b0   = scan << 4;         // scan's batch base
    const int bq   = b0 + (q << 2);
    const int fbase = scan << 6;        // 64 flags per scan

    // ---- stage weight slices (16 cols x 3 gates) into LDS ----
    #pragma unroll
    for (int c = 0; c < 32; ++c) {
        int idx = tid + c * 64;          // 0..2047 16B chunks
        int kkg = idx >> 6;
        int rem = idx & 63;
        int qq  = rem >> 4;
        int rr  = rem & 15;
        size_t so = (size_t)(col0 + rr) * HIDDEN + kkg * 32 + qq * 8;
        *(short8*)&WzL[idx * 8] = *(const short8*)&Wzh[so];
        *(short8*)&WrL[idx * 8] = *(const short8*)&Wrh[so];
        *(short8*)&WhL[idx * 8] = *(const short8*)&Whh[so];
    }
    __syncthreads();

    const float bzj = bz[j], brj = br[j], bhj = bh[j];

    float zreg[4] = {0.f, 0.f, 0.f, 0.f};
    float Hreg[4] = {0.f, 0.f, 0.f, 0.f};
    int p = 0;

    // ---- prologue: tokens + embeddings for t=0 ----
    float ezc[4], erc[4], ehc[4];
    {
        int tk[4];
        #pragma unroll
        for (int r = 0; r < 4; ++r) tk[r] = X[(bq + r) * SEQ + 0];
        #pragma unroll
        for (int r = 0; r < 4; ++r) {
            ezc[r] = Wz[(size_t)tk[r] * HIDDEN + j];
            erc[r] = Wr[(size_t)tk[r] * HIDDEN + j];
            ehc[r] = Wh[(size_t)tk[r] * HIDDEN + j];
        }
    }

    for (int t = 0; t < SEQ; ++t) {
        const int tn = (t + 1 < SEQ) ? t + 1 : t;   // clamped: constant load counts
        int tokn[4];
        float ezn[4], ern[4], ehn[4];

        // ---------------- phase 1: z and r ----------------
        {
            const unsigned short* ap = Hbf + (size_t)(b0 + row) * HIDDEN + kq;
            short8 A[32];
            #pragma unroll
            for (int kk = 0; kk < 32; ++kk)
                A[kk] = cld16(ap + kk * 32);
            #pragma unroll
            for (int r = 0; r < 4; ++r) {
                const int* px = X + (bq + r) * SEQ + tn;
                asm volatile("global_load_dword %0, %1, off" : "=v"(tokn[r]) : "v"(px) : "memory");
            }

            f32x4 accZ = {0.f, 0.f, 0.f, 0.f}, accR = {0.f, 0.f, 0.f, 0.f};
            asm volatile("s_waitcnt vmcnt(20)" ::: "memory");   // 36-20=16: A[0..15] retired
            __builtin_amdgcn_sched_barrier(0);
            #pragma unroll
            for (int kk = 0; kk < 16; ++kk) {
                int lo = kk * 512 + q * 128 + row * 8;
                short8 fz = *(const short8*)&WzL[lo];
                short8 fr = *(const short8*)&WrL[lo];
                accZ = __builtin_amdgcn_mfma_f32_16x16x32_bf16(A[kk], fz, accZ, 0, 0, 0);
                accR = __builtin_amdgcn_mfma_f32_16x16x32_bf16(A[kk], fr, accR, 0, 0, 0);
            }
            asm volatile("s_waitcnt vmcnt(4)" ::: "memory");    // all A retired; tokens fly
            __builtin_amdgcn_sched_barrier(0);
            #pragma unroll
            for (int kk = 16; kk < 32; ++kk) {
                int lo = kk * 512 + q * 128 + row * 8;
                short8 fz = *(const short8*)&WzL[lo];
                short8 fr = *(const short8*)&WrL[lo];
                accZ = __builtin_amdgcn_mfma_f32_16x16x32_bf16(A[kk], fz, accZ, 0, 0, 0);
                accR = __builtin_amdgcn_mfma_f32_16x16x32_bf16(A[kk], fr, accR, 0, 0, 0);
            }
            // r first: its stores gate the barrier
            #pragma unroll
            for (int r = 0; r < 4; ++r) {
                float rv = 1.f / (1.f + expf(-(accR[r] + erc[r] + brj)));
                ast16(&rHbf[(bq + r) * HIDDEN + j], f2bf(rv * Hreg[r]));
            }
            #pragma unroll
            for (int r = 0; r < 4; ++r)
                zreg[r] = 1.f / (1.f + expf(-(accZ[r] + ezc[r] + bzj)));
        }

        scan_barrier(flags, fbase, cg, ++p);   // tokens retired inside (vmcnt(0))

        // ---------------- phase 2: h + state update ----------------
        {
            const unsigned short* ap = rHbf + (size_t)(b0 + row) * HIDDEN + kq;
            short8 A[32];
            #pragma unroll
            for (int kk = 0; kk < 32; ++kk)
                A[kk] = cld16(ap + kk * 32);
            // 12 embedding gathers for t+1: fly under MFMA + epilogue + store drain
            #pragma unroll
            for (int r = 0; r < 4; ++r) {
                const float* pz = Wz + (size_t)tokn[r] * HIDDEN + j;
                const float* pr = Wr + (size_t)tokn[r] * HIDDEN + j;
                const float* pm = Wh + (size_t)tokn[r] * HIDDEN + j;
                asm volatile("global_load_dword %0, %1, off" : "=v"(ezn[r]) : "v"(pz) : "memory");
                asm volatile("global_load_dword %0, %1, off" : "=v"(ern[r]) : "v"(pr) : "memory");
                asm volatile("global_load_dword %0, %1, off" : "=v"(ehn[r]) : "v"(pm) : "memory");
            }

            f32x4 accA = {0.f, 0.f, 0.f, 0.f}, accB = {0.f, 0.f, 0.f, 0.f};
            asm volatile("s_waitcnt vmcnt(28)" ::: "memory");   // 44-28=16: A[0..15] retired
            __builtin_amdgcn_sched_barrier(0);
            #pragma unroll
            for (int kk = 0; kk < 16; ++kk) {
                int lo = kk * 512 + q * 128 + row * 8;
                short8 fh = *(const short8*)&WhL[lo];
                if (kk & 1) accB = __builtin_amdgcn_mfma_f32_16x16x32_bf16(A[kk], fh, accB, 0, 0, 0);
                else        accA = __builtin_amdgcn_mfma_f32_16x16x32_bf16(A[kk], fh, accA, 0, 0, 0);
            }
            asm volatile("s_waitcnt vmcnt(12)" ::: "memory");   // all A retired; gathers fly
            __builtin_amdgcn_sched_barrier(0);
            #pragma unroll
            for (int kk = 16; kk < 32; ++kk) {
                int lo = kk * 512 + q * 128 + row * 8;
                short8 fh = *(const short8*)&WhL[lo];
                if (kk & 1) accB = __builtin_amdgcn_mfma_f32_16x16x32_bf16(A[kk], fh, accB, 0, 0, 0);
                else        accA = __builtin_amdgcn_mfma_f32_16x16x32_bf16(A[kk], fh, accA, 0, 0, 0);
            }
            #pragma unroll
            for (int r = 0; r < 4; ++r) {
                int b = bq + r;
                float h  = tanhf(accA[r] + accB[r] + ehc[r] + bhj);
                float Hn = zreg[r] * h + (1.f - zreg[r]) * Hreg[r];
                Hreg[r] = Hn;
                unsigned short bfv = f2bf(Hn);
                ast16(&Hbf[b * HIDDEN + j], bfv);
                Hhist[(size_t)t * (BATCH * HIDDEN) + b * HIDDEN + j] = bfv;
                if (t == SEQ - 1) Hf[b * HIDDEN + j] = Hn;
            }
        }

        scan_barrier(flags, fbase, cg, ++p);   // gathers retired inside (vmcnt(0))

        #pragma unroll
        for (int r = 0; r < 4; ++r) { ezc[r] = ezn[r]; erc[r] = ern[r]; ehc[r] = ehn[r]; }
    }
}

// ---------------- fallback step kernels (round-1 proven) ----------------
__global__ __launch_bounds__(256) void k_step1(
    const int* __restrict__ X,
    const float* __restrict__ Wz, const float* __restrict__ bz,
    const float* __restrict__ Wr, const float* __restrict__ br,
    const unsigned short* __restrict__ Wzh, const unsigned short* __restrict__ Wrh,
    const unsigned short* __restrict__ Hbf, const float* __restrict__ Hf,
    float* __restrict__ zbuf, unsigned short* __restrict__ rHbf, int t)
{
    int w    = threadIdx.x >> 6;
    int lane = threadIdx.x & 63;
    int nt = blockIdx.x;
    int mt = w;
    bool isz = nt < 64;
    const unsigned short* W = isz ? Wzh : Wrh;
    int ntl = nt & 63;
    int row = lane & 15;
    int kq  = (lane >> 4) << 3;
    const unsigned short* aptr = Hbf + (size_t)(mt * 16 + row) * HIDDEN + kq;
    const unsigned short* bptr = W   + (size_t)(ntl * 16 + row) * HIDDEN + kq;
    f32x4 acc = {0.f, 0.f, 0.f, 0.f};
    #pragma unroll 8
    for (int kk = 0; kk < HIDDEN / 32; ++kk) {
        short8 a = *(const short8*)(aptr + kk * 32);
        short8 b = *(const short8*)(bptr + kk * 32);
        acc = __builtin_amdgcn_mfma_f32_16x16x32_bf16(a, b, acc, 0, 0, 0);
    }
    int j = ntl * 16 + row;
    const float* Wemb = isz ? Wz : Wr;
    float bias = isz ? bz[j] : br[j];
    #pragma unroll
    for (int r = 0; r < 4; ++r) {
        int b = mt * 16 + ((lane >> 4) << 2) + r;
        int tok = X[b * SEQ + t];
        float pre = acc[r] + Wemb[(size_t)tok * HIDDEN + j] + bias;
        float s = 1.f / (1.f + expf(-pre));
        if (isz) zbuf[b * HIDDEN + j] = s;
        else     rHbf[b * HIDDEN + j] = f2bf(s * Hf[b * HIDDEN + j]);
    }
}

__global__ __launch_bounds__(256) void k_step2(
    const int* __restrict__ X,
    const float* __restrict__ Wh, const float* __restrict__ bh,
    const unsigned short* __restrict__ Whh,
    const unsigned short* __restrict__ rHbf,
    const float* __restrict__ zbuf,
    float* __restrict__ Hf, unsigned short* __restrict__ Hbf,
    unsigned short* __restrict__ Hhist, int t)
{
    int w    = threadIdx.x >> 6;
    int lane = threadIdx.x & 63;
    int nt = blockIdx.x;
    int mt = w;
    int row = lane & 15;
    int kq  = (lane >> 4) << 3;
    const unsigned short* aptr = rHbf + (size_t)(mt * 16 + row) * HIDDEN + kq;
    const unsigned short* bptr = Whh  + (size_t)(nt * 16 + row) * HIDDEN + kq;
    f32x4 acc = {0.f, 0.f, 0.f, 0.f};
    #pragma unroll 8
    for (int kk = 0; kk < HIDDEN / 32; ++kk) {
        short8 a = *(const short8*)(aptr + kk * 32);
        short8 b = *(const short8*)(bptr + kk * 32);
        acc = __builtin_amdgcn_mfma_f32_16x16x32_bf16(a, b, acc, 0, 0, 0);
    }
    int j = nt * 16 + row;
    float bias = bh[j];
    #pragma unroll
    for (int r = 0; r < 4; ++r) {
        int b = mt * 16 + ((lane >> 4) << 2) + r;
        int tok = X[b * SEQ + t];
        float pre = acc[r] + Wh[(size_t)tok * HIDDEN + j] + bias;
        float h = tanhf(pre);
        float z = zbuf[b * HIDDEN + j];
        float Hold = Hf[b * HIDDEN + j];
        float Hn = z * h + (1.f - z) * Hold;
        Hf[b * HIDDEN + j] = Hn;
        unsigned short bf = f2bf(Hn);
        Hbf[b * HIDDEN + j] = bf;
        Hhist[(size_t)t * (BATCH * HIDDEN) + b * HIDDEN + j] = bf;
    }
}

// ---------------- output projection ----------------
__global__ __launch_bounds__(256) void k_out(
    const unsigned short* __restrict__ A,
    const unsigned short* __restrict__ B,
    const float* __restrict__ bo,
    float* __restrict__ out)
{
    __shared__ __align__(16) unsigned short As[128 * 32];
    __shared__ __align__(16) unsigned short Bs[128 * 32];
    int bn = blockIdx.x & 31;
    int bm = blockIdx.x >> 5;
    int m0 = bm << 7, n0 = bn << 7;
    int tid  = threadIdx.x;
    int w    = tid >> 6, lane = tid & 63;
    int wm = w & 1, wn = w >> 1;
    int row = lane & 15;
    int kq  = (lane >> 4) << 3;

    f32x4 acc[4][4];
    #pragma unroll
    for (int i = 0; i < 4; ++i)
        #pragma unroll
        for (int jj = 0; jj < 4; ++jj)
            acc[i][jj] = (f32x4){0.f, 0.f, 0.f, 0.f};

    for (int k0 = 0; k0 < HIDDEN; k0 += 32) {
        #pragma unroll
        for (int c = 0; c < 2; ++c) {
            int off  = tid * 32 + c * 16;
            int rowi = off >> 6;
            int us   = (off & 63) >> 1;
            *(short8*)&As[rowi * 32 + us] =
                *(const short8*)&A[(size_t)(m0 + rowi) * HIDDEN + k0 + us];
            *(short8*)&Bs[rowi * 32 + us] =
                *(const short8*)&B[(size_t)(n0 + rowi) * HIDDEN + k0 + us];
        }
        __syncthreads();
        short8 a[4], b[4];
        #pragma unroll
        for (int i = 0; i < 4; ++i)
            a[i] = *(const short8*)&As[(wm * 64 + i * 16 + row) * 32 + kq];
        #pragma unroll
        for (int jj = 0; jj < 4; ++jj)
            b[jj] = *(const short8*)&Bs[(wn * 64 + jj * 16 + row) * 32 + kq];
        #pragma unroll
        for (int i = 0; i < 4; ++i)
            #pragma unroll
            for (int jj = 0; jj < 4; ++jj)
                acc[i][jj] = __builtin_amdgcn_mfma_f32_16x16x32_bf16(a[i], b[jj], acc[i][jj], 0, 0, 0);
        __syncthreads();
    }

    #pragma unroll
    for (int i = 0; i < 4; ++i) {
        #pragma unroll
        for (int jj = 0; jj < 4; ++jj) {
            int n = n0 + wn * 64 + jj * 16 + row;
            float bb = bo[n];
            #pragma unroll
            for (int r = 0; r < 4; ++r) {
                int m = m0 + wm * 64 + i * 16 + ((lane >> 4) << 2) + r;
                out[(size_t)m * VOCAB + n] = acc[i][jj][r] + bb;
            }
        }
    }
}

// ---------------- H_final copy ----------------
__global__ __launch_bounds__(256) void k_copyH(const float* __restrict__ Hf,
                                               float* __restrict__ out) {
    int i = blockIdx.x * 256 + threadIdx.x;
    if (i < BATCH * HIDDEN)
        out[(size_t)SEQ * BATCH * VOCAB + i] = Hf[i];
}

extern "C" void kernel_launch(void* const* d_in, const int* in_sizes, int n_in,
                              void* d_out, int out_size, void* d_ws, size_t ws_size,
                              hipStream_t stream) {
    const int*   X  = (const int*)  d_in[0];
    const float* Wz = (const float*)d_in[1];
    const float* bz = (const float*)d_in[2];
    const float* Wr = (const float*)d_in[3];
    const float* br = (const float*)d_in[4];
    const float* Wh = (const float*)d_in[5];
    const float* bh = (const float*)d_in[6];
    const float* Wo = (const float*)d_in[7];
    const float* bo = (const float*)d_in[8];
    float* out = (float*)d_out;
    char* ws = (char*)d_ws;

    float*          Hf    = (float*)(ws);                           // 256KB
    float*          zbuf  = (float*)(ws + (256 << 10));             // 256KB (fallback only)
    int*            flags = (int*)(ws + (512 << 10));               // 8KB
    unsigned short* Hbf   = (unsigned short*)(ws + (528 << 10));    // 128KB
    unsigned short* rHbf  = (unsigned short*)(ws + (656 << 10));    // 128KB
    unsigned short* Wzh   = (unsigned short*)(ws + (1 << 20));      // 2MB
    unsigned short* Wrh   = Wzh + 1024 * 1024;                      // 2MB
    unsigned short* Whh   = Wrh + 1024 * 1024;                      // 2MB
    unsigned short* WoT   = Whh + 1024 * 1024;                      // 8MB
    unsigned short* Hhist = WoT + (size_t)VOCAB * HIDDEN;           // 32MB

    k_zero<<<256, 256, 0, stream>>>(Hf, Hbf, flags);
    k_pack<<<32 * 32,  256, 0, stream>>>(Wz + (size_t)VOCAB * HIDDEN, Wzh, 1024, 1024);
    k_pack<<<32 * 32,  256, 0, stream>>>(Wr + (size_t)VOCAB * HIDDEN, Wrh, 1024, 1024);
    k_pack<<<32 * 32,  256, 0, stream>>>(Wh + (size_t)VOCAB * HIDDEN, Whh, 1024, 1024);
    k_pack<<<32 * 128, 256, 0, stream>>>(Wo, WoT, 1024, 4096);

    void* args[] = {
        (void*)&X, (void*)&Wz, (void*)&bz, (void*)&Wr, (void*)&br,
        (void*)&Wh, (void*)&bh, (void*)&Wzh, (void*)&Wrh, (void*)&Whh,
        (void*)&Hf, (void*)&Hbf, (void*)&rHbf, (void*)&Hhist, (void*)&flags
    };
    hipError_t cerr = hipLaunchCooperativeKernel((void*)k_scan, dim3(NWG), dim3(64),
                                                 args, 0, stream);
    if (cerr != hipSuccess) {
        for (int t = 0; t < SEQ; ++t) {
            k_step1<<<128, 256, 0, stream>>>(X, Wz, bz, Wr, br, Wzh, Wrh, Hbf, Hf, zbuf, rHbf, t);
            k_step2<<<64,  256, 0, stream>>>(X, Wh, bh, Whh, rHbf, zbuf, Hf, Hbf, Hhist, t);
        }
    }

    k_out<<<4096, 256, 0, stream>>>(Hhist, WoT, bo, out);
    k_copyH<<<256, 256, 0, stream>>>(Hf, out);
}